// Round 1
// baseline (96.687 us; speedup 1.0000x reference)
//
#include <hip/hip_runtime.h>
#include <hip/hip_bf16.h>

// Problem constants
#define NF 40   // fields f
#define NI 40   // in_sub i
#define NN 40   // out_sub n
#define ED 64   // embed D, d
#define NB 256  // batch b

typedef __attribute__((ext_vector_type(8))) short   short8;
typedef __attribute__((ext_vector_type(8))) __bf16  bf16x8;
typedef __attribute__((ext_vector_type(4))) float   f32x4;

__device__ __forceinline__ unsigned short f2bf(float x) {
    union { float f; unsigned u; } v; v.f = x;
    unsigned r = v.u + 0x7FFFu + ((v.u >> 16) & 1u);   // RNE
    return (unsigned short)(r >> 16);
}

__device__ __forceinline__ bf16x8 ld_frag(const unsigned short* p) {
    return __builtin_bit_cast(bf16x8, *(const short8*)p);
}

__device__ __forceinline__ f32x4 mfma16(bf16x8 a, bf16x8 b, f32x4 c) {
    return __builtin_amdgcn_mfma_f32_16x16x32_bf16(a, b, c, 0, 0, 0);
}

__device__ __forceinline__ float4 mul4(const float4 a, const float4 b) {
    float4 r; r.x = a.x * b.x; r.y = a.y * b.y; r.z = a.z * b.z; r.w = a.w * b.w;
    return r;
}

__device__ __forceinline__ bf16x8 pack8(const float4 a, const float4 b) {
    short8 s;
    s[0] = (short)f2bf(a.x); s[1] = (short)f2bf(a.y);
    s[2] = (short)f2bf(a.z); s[3] = (short)f2bf(a.w);
    s[4] = (short)f2bf(b.x); s[5] = (short)f2bf(b.y);
    s[6] = (short)f2bf(b.z); s[7] = (short)f2bf(b.w);
    return __builtin_bit_cast(bf16x8, s);
}

// ==========================================================================
// R12: WORKSPACE-FREE fused kernel. The rocprof top-5 shows the timed region
// is dominated by a 256 MiB fillBufferAligned (41.5 us) = the harness's d_ws
// re-poison. Using d_ws costs more than the whole compute. This kernel fuses
// the param prep (whp/alp) into each block:
//   - whB fragments: loaded directly from f32 W (8 contiguous floats/lane,
//     L2/L3-hot, 655 KB total) * h, converted in-register.
//   - alA fragments: alpha[:,:,n0:n0+4] staged once per block via LDS
//     transpose (float4 over the n-contiguous axis), bf16 [n'][i(48)][f(64)]
//     with zero pads -- identical layout/content to the old ws 'alp'.
// The b-loop / MFMA body / output path are byte-identical to verified main8b.
// LDS = 16.1 KB (sBi/sBT) + 24.6 KB (sAl) = 40.7 KB -> 3-4 blocks/CU.
// ==========================================================================
#define BPB 2             // b's per block (keeps main8b's validated TLP shape)
#define PSM 72            // padded stride for sBi/sBT (bank-conflict-free)
#define ALS (48 * 64)     // shorts per n in sAl

__global__ __launch_bounds__(256, 2) void gif_fused(
        const float* __restrict__ B0, const float* __restrict__ Bi,
        const float* __restrict__ W, const float* __restrict__ alpha,
        const float* __restrict__ h, float* __restrict__ out) {
    const int bg = blockIdx.x;         // 0..127 : b in [bg*BPB, bg*BPB+BPB)
    const int ng = blockIdx.y;         // 0..9   : n in [ng*4, ng*4+4)
    const int t = threadIdx.x;
    const int lane = t & 63, w = t >> 6;
    const int quad = lane >> 4, l15 = lane & 15, fo = quad * 8;
    const int n = ng * 4 + w;

    __shared__ __align__(16) unsigned short sBi[48 * PSM];   // [i][d]  6912 B
    __shared__ __align__(16) unsigned short sBT[64 * PSM];   // [D][f]  9216 B
    __shared__ __align__(16) unsigned short sAl[4 * ALS];    // [n'][i][f] 24576 B

    // ---- 1. staging loads for first b issued FIRST (coalesced float4) ----
    float4 rbi[3], rb0[3];
    {
        const float4* biv = (const float4*)(Bi + (size_t)(bg * BPB) * NI * ED);
        const float4* b0v = (const float4*)(B0 + (size_t)(bg * BPB) * NF * ED);
#pragma unroll
        for (int k = 0; k < 3; ++k) {
            const int c = t + k * 256;
            if (c < 640) { rbi[k] = biv[c]; rb0[k] = b0v[c]; }
        }
    }

    // ---- 2. W/h fragment source loads (f32, L2/L3-hot; 16B aligned) ----
    float4 wf[4][2][2];   // [tt][s][half] -> W[n][tt*16+l15][s*32+fo + 0..7]
    float4 hv[2][2];      // h[n][s*32+fo + 0..7]
    {
        const float* wp = W + (size_t)n * ED * ED;
#pragma unroll
        for (int tt = 0; tt < 4; ++tt)
#pragma unroll
            for (int s = 0; s < 2; ++s) {
                const float* p = wp + (tt * 16 + l15) * ED + s * 32 + fo;
                wf[tt][s][0] = *(const float4*)p;
                wf[tt][s][1] = *(const float4*)(p + 4);
            }
#pragma unroll
        for (int s = 0; s < 2; ++s) {
            const float* p = h + n * ED + s * 32 + fo;
            hv[s][0] = *(const float4*)p;
            hv[s][1] = *(const float4*)(p + 4);
        }
    }

    // ---- 3. alpha -> sAl transpose staging (float4 over contiguous n) ----
    // alpha[(f*NI+i)*NN + n0 + 0..3] = float4 at index e*(NN/4)+ng, e=f*NI+i.
    {
        const float4* av = (const float4*)alpha;
#pragma unroll
        for (int k = 0; k < 7; ++k) {
            const int e = t + k * 256;
            if (e < NF * NI) {
                const int f = e / NI, i = e - f * NI;
                const float4 a4 = av[e * (NN / 4) + ng];
                sAl[0 * ALS + i * 64 + f] = f2bf(a4.x);
                sAl[1 * ALS + i * 64 + f] = f2bf(a4.y);
                sAl[2 * ALS + i * 64 + f] = f2bf(a4.z);
                sAl[3 * ALS + i * 64 + f] = f2bf(a4.w);
            }
        }
        for (int idx = t; idx < 4 * 8 * 64; idx += 256) {    // rows i 40..47
            const int np = idx >> 9, rem = idx & 511;
            sAl[np * ALS + (40 + (rem >> 6)) * 64 + (rem & 63)] = 0;
        }
        for (int idx = t; idx < 4 * 40 * 24; idx += 256) {   // cols f 40..63
            const int np = idx / 960, rem = idx - np * 960;
            const int i = rem / 24, f = 40 + rem - i * 24;
            sAl[np * ALS + i * 64 + f] = 0;
        }
    }

    // ---- 4. sBi/sBT pads + convert/write first b's staging ----
    for (int idx = t; idx < 8 * 64; idx += 256)          // sBi rows i 40..47
        sBi[(40 + (idx >> 6)) * PSM + (idx & 63)] = 0;
    for (int idx = t; idx < 64 * 24; idx += 256) {       // sBT cols f 40..63
        int D = idx / 24, f = 40 + idx - D * 24;
        sBT[D * PSM + f] = 0;
    }
#pragma unroll
    for (int k = 0; k < 3; ++k) {
        const int c = t + k * 256;
        if (c < 640) {
            const int r = c >> 4, col = (c & 15) * 4;
            ushort4 pk;
            pk.x = f2bf(rbi[k].x); pk.y = f2bf(rbi[k].y);
            pk.z = f2bf(rbi[k].z); pk.w = f2bf(rbi[k].w);
            *(ushort4*)&sBi[r * PSM + col] = pk;
            sBT[(col + 0) * PSM + r] = f2bf(rb0[k].x);
            sBT[(col + 1) * PSM + r] = f2bf(rb0[k].y);
            sBT[(col + 2) * PSM + r] = f2bf(rb0[k].z);
            sBT[(col + 3) * PSM + r] = f2bf(rb0[k].w);
        }
    }
    __syncthreads();

    // ---- 5. build this wave's register param fragments (once) ----
    bf16x8 whB[4][2];
#pragma unroll
    for (int tt = 0; tt < 4; ++tt)
#pragma unroll
        for (int s = 0; s < 2; ++s)
            whB[tt][s] = pack8(mul4(wf[tt][s][0], hv[s][0]),
                               mul4(wf[tt][s][1], hv[s][1]));
    bf16x8 alA[3][2];
    {
        const unsigned short* ap = &sAl[w * ALS];
#pragma unroll
        for (int m = 0; m < 3; ++m)
#pragma unroll
            for (int s = 0; s < 2; ++s)
                alA[m][s] = ld_frag(&ap[(m * 16 + l15) * 64 + s * 32 + fo]);
    }

    // ---- 6. b-loop (byte-identical to verified main8b) ----
#pragma unroll
    for (int j = 0; j < BPB; ++j) {
        const int b = bg * BPB + j;

        if (j < BPB - 1) {   // prefetch next b's staging into registers
            const float4* biv = (const float4*)(Bi + (size_t)(b + 1) * NI * ED);
            const float4* b0v = (const float4*)(B0 + (size_t)(b + 1) * NF * ED);
#pragma unroll
            for (int k = 0; k < 3; ++k) {
                const int c = t + k * 256;
                if (c < 640) { rbi[k] = biv[c]; rb0[k] = b0v[c]; }
            }
        }

        // per-b fragments from LDS + 48-MFMA body
        bf16x8 biA[3][2];
#pragma unroll
        for (int m = 0; m < 3; ++m)
#pragma unroll
            for (int s = 0; s < 2; ++s)
                biA[m][s] = ld_frag(&sBi[(m * 16 + l15) * PSM + s * 32 + fo]);

        float p[4];
#pragma unroll
        for (int tt = 0; tt < 4; ++tt) {
            bf16x8 bb0 = ld_frag(&sBT[(tt * 16 + l15) * PSM + fo]);
            bf16x8 bb1 = ld_frag(&sBT[(tt * 16 + l15) * PSM + 32 + fo]);
            float acc = 0.f;
#pragma unroll
            for (int m = 0; m < 3; ++m) {
                f32x4 z = {0.f, 0.f, 0.f, 0.f};
                f32x4 T = mfma16(biA[m][0], whB[tt][0], z);
                T = mfma16(biA[m][1], whB[tt][1], T);
                f32x4 G = mfma16(alA[m][0], bb0, z);
                G = mfma16(alA[m][1], bb1, G);
                acc += T[0] * G[0] + T[1] * G[1] + T[2] * G[2] + T[3] * G[3];
            }
            p[tt] = acc;
        }
#pragma unroll
        for (int tt = 0; tt < 4; ++tt) {
            p[tt] += __shfl_xor(p[tt], 16, 64);
            p[tt] += __shfl_xor(p[tt], 32, 64);
        }
        float v = (quad == 0) ? p[0] : (quad == 1) ? p[1] : (quad == 2) ? p[2] : p[3];
        out[((size_t)b * NN + n) * ED + lane] = v;

        if (j < BPB - 1) {   // restage for b+1 between two barriers
            __syncthreads();
#pragma unroll
            for (int k = 0; k < 3; ++k) {
                const int c = t + k * 256;
                if (c < 640) {
                    const int r = c >> 4, col = (c & 15) * 4;
                    ushort4 pk;
                    pk.x = f2bf(rbi[k].x); pk.y = f2bf(rbi[k].y);
                    pk.z = f2bf(rbi[k].z); pk.w = f2bf(rbi[k].w);
                    *(ushort4*)&sBi[r * PSM + col] = pk;
                    sBT[(col + 0) * PSM + r] = f2bf(rb0[k].x);
                    sBT[(col + 1) * PSM + r] = f2bf(rb0[k].y);
                    sBT[(col + 2) * PSM + r] = f2bf(rb0[k].z);
                    sBT[(col + 3) * PSM + r] = f2bf(rb0[k].w);
                }
            }
            __syncthreads();
        }
    }
}

// ==========================================================================
// Launch: NO workspace use at all (d_ws untouched -> no 256 MiB poison cost
// if the harness's re-poison is usage-conditional; either way, one kernel
// replaces prep4+main8b).
// ==========================================================================
extern "C" void kernel_launch(void* const* d_in, const int* in_sizes, int n_in,
                              void* d_out, int out_size, void* d_ws, size_t ws_size,
                              hipStream_t stream) {
    const float* B0    = (const float*)d_in[0];  // (256,40,64)
    const float* Bi    = (const float*)d_in[1];  // (256,40,64)
    const float* W     = (const float*)d_in[2];  // (40,64,64)
    const float* alpha = (const float*)d_in[3];  // (40,40,40)
    const float* h     = (const float*)d_in[4];  // (40,64,1)
    float* out = (float*)d_out;                  // (256,40,64)

    (void)d_ws; (void)ws_size;
    gif_fused<<<dim3(NB / BPB, 10), 256, 0, stream>>>(B0, Bi, W, alpha, h, out);
}

// Round 2
// 79.561 us; speedup vs baseline: 1.2153x; 1.2153x over previous
//
#include <hip/hip_runtime.h>
#include <hip/hip_bf16.h>

// Problem constants
#define NF 40   // fields f
#define NI 40   // in_sub i
#define NN 40   // out_sub n
#define ED 64   // embed D, d
#define NB 256  // batch b

typedef __attribute__((ext_vector_type(8))) short   short8;
typedef __attribute__((ext_vector_type(8))) __bf16  bf16x8;
typedef __attribute__((ext_vector_type(4))) float   f32x4;

__device__ __forceinline__ unsigned short f2bf(float x) {
    union { float f; unsigned u; } v; v.f = x;
    unsigned r = v.u + 0x7FFFu + ((v.u >> 16) & 1u);   // RNE
    return (unsigned short)(r >> 16);
}

__device__ __forceinline__ bf16x8 ld_frag(const unsigned short* p) {
    return __builtin_bit_cast(bf16x8, *(const short8*)p);
}

__device__ __forceinline__ f32x4 mfma16(bf16x8 a, bf16x8 b, f32x4 c) {
    return __builtin_amdgcn_mfma_f32_16x16x32_bf16(a, b, c, 0, 0, 0);
}

// ==========================================================================
// R13 architecture. Lesson from R12: the 256 MiB ws poison (~41 us) is
// UNCONDITIONAL -> ws usage is free; minimize kernel time instead.
// main8b's ~36 us was dominated by per-block VALU staging (640 f2bf + B0
// scatter-transpose, x10 redundant across ng-blocks, 3 barriers). R13 moves
// ALL conversion/transpose/pad/swizzle work into prep (once per b):
//   ws layout:
//     whp[n][D64][d64]  bf16  (W*h, fragment-ready)          [verified R5]
//     alp[n][i48][f64]  bf16  (alpha^T, pads zeroed)         [verified R5]
//     bft[b] = { Bi[i48][d64] | B0T[D64][f64] } bf16, 14336 B contiguous,
//              pads zeroed, 16B-chunk XOR swizzle (chunk ^= row&7) baked in
//              so main's stride-128B ds_read_b128 is bank-conflict-free
//              without padding (G4/T2).
// main9: 7 coalesced b128 loads + 7 linear ds_write_b128 per thread (both
// b's), param gathers, ONE __syncthreads, then pure MFMA. No f2bf, no
// scatter, no pad writes, no restage barriers.
// ==========================================================================
#define WHP_N (64 * 64)   // 4096 shorts per n
#define ALP_N (48 * 64)   // 3072 shorts per n
#define BFT_N 7168        // shorts per b: 48*64 (Bi) + 64*64 (B0T)
#define BI_OFF 0
#define B0T_OFF (48 * 64) // 3072
#define BPB 2             // b's per block in main

// --------------------------------------------------------------------------
// prep5: grid (NN + NF + NB) x 256.
//   x < 40        : whp for n=x, + alp pad zeroing for n=x   (verified R5)
//   40 <= x < 80  : alp transpose fill for f=x-40            (verified R5)
//   x >= 80       : b-tile conversion for b=x-80
// --------------------------------------------------------------------------
__global__ __launch_bounds__(256) void gif_prep5(
        const float* __restrict__ B0, const float* __restrict__ Bi,
        const float* __restrict__ W, const float* __restrict__ alpha,
        const float* __restrict__ h,
        unsigned short* __restrict__ whp, unsigned short* __restrict__ alp,
        unsigned short* __restrict__ bft) {
    const int x = blockIdx.x;
    const int t = threadIdx.x;
    if (x < NN) {
        const int n = x;
        for (int idx = t; idx < 64 * 64; idx += 256) {       // whp coalesced
            int d = idx & 63;
            whp[n * WHP_N + idx] = f2bf(W[n * ED * ED + idx] * h[n * ED + d]);
        }
        for (int idx = t; idx < 8 * 64; idx += 256)          // alp rows i 40..47
            alp[n * ALP_N + (40 + (idx >> 6)) * 64 + (idx & 63)] = 0;
        for (int idx = t; idx < 40 * 24; idx += 256) {       // alp cols f 40..63
            int i = idx / 24, f = 40 + idx - i * 24;
            alp[n * ALP_N + i * 64 + f] = 0;
        }
    } else if (x < NN + NF) {
        const int f = x - NN;
        for (int idx = t; idx < NI * NN; idx += 256) {       // coalesced read
            int i = idx / NN, n = idx - i * NN;
            alp[n * ALP_N + i * 64 + f] = f2bf(alpha[(f * NI + i) * NN + n]);
        }
    } else {
        const int b = x - (NN + NF);
        unsigned short* dst = bft + (size_t)b * BFT_N;
        __shared__ __align__(16) unsigned short sT[64 * 72]; // B0T staging

        // coalesced float4 reads of this b's Bi and B0
        const float4* biv = (const float4*)(Bi + (size_t)b * NI * ED);
        const float4* b0v = (const float4*)(B0 + (size_t)b * NF * ED);
        float4 rb[3], r0[3];
#pragma unroll
        for (int k = 0; k < 3; ++k) {
            const int c = t + k * 256;
            if (c < 640) { rb[k] = biv[c]; r0[k] = b0v[c]; }
        }

        // zero sT pad cols f 40..71 (only 40..63 ever read)
        for (int idx = t; idx < 64 * 32; idx += 256)
            sT[(idx >> 5) * 72 + 40 + (idx & 31)] = 0;

        // Bi: write swizzled bf16 rows directly (ushort4, 8B aligned)
#pragma unroll
        for (int k = 0; k < 3; ++k) {
            const int c = t + k * 256;
            if (c < 640) {
                const int i = c >> 4, d0 = (c & 15) * 4;
                ushort4 pk;
                pk.x = f2bf(rb[k].x); pk.y = f2bf(rb[k].y);
                pk.z = f2bf(rb[k].z); pk.w = f2bf(rb[k].w);
                const int chunk = (d0 >> 3) ^ (i & 7);
                *(ushort4*)&dst[BI_OFF + i * 64 + (chunk << 3) + (d0 & 7)] = pk;
            }
        }
        for (int idx = t; idx < 8 * 64; idx += 256)          // Bi pad rows
            dst[BI_OFF + (40 + (idx >> 6)) * 64 + (idx & 63)] = 0;

        // B0 -> sT transpose (sT[D][f] = B0[b][f][D])
#pragma unroll
        for (int k = 0; k < 3; ++k) {
            const int c = t + k * 256;
            if (c < 640) {
                const int f = c >> 4, D0 = (c & 15) * 4;
                sT[(D0 + 0) * 72 + f] = f2bf(r0[k].x);
                sT[(D0 + 1) * 72 + f] = f2bf(r0[k].y);
                sT[(D0 + 2) * 72 + f] = f2bf(r0[k].z);
                sT[(D0 + 3) * 72 + f] = f2bf(r0[k].w);
            }
        }
        __syncthreads();

        // sT -> dst B0T, swizzled, coalesced short8 writes
        for (int g = t; g < 512; g += 256) {
            const int D = g >> 3, pc = g & 7;        // physical chunk pc
            short8 v = *(const short8*)&sT[D * 72 + ((pc ^ (D & 7)) << 3)];
            *(short8*)&dst[B0T_OFF + D * 64 + (pc << 3)] = v;
        }
    }
}

// --------------------------------------------------------------------------
// main9: grid (128, 10) x 256 thr (4 waves). Wave w owns n = ng*4 + w.
// --------------------------------------------------------------------------
__global__ __launch_bounds__(256, 2) void gif_main9(
        const unsigned short* __restrict__ whp,
        const unsigned short* __restrict__ alp,
        const unsigned short* __restrict__ bft,
        float* __restrict__ out) {
    const int bg = blockIdx.x;         // 0..127 : b in [bg*2, bg*2+2)
    const int ng = blockIdx.y;         // 0..9   : n in [ng*4, ng*4+4)
    const int t = threadIdx.x;
    const int lane = t & 63, w = t >> 6;
    const int quad = lane >> 4, l15 = lane & 15, fo = quad * 8;
    const int n = ng * 4 + w;

    __shared__ __align__(16) unsigned short sBuf[2 * BFT_N];   // 28672 B

    // ---- 1. register-stage BOTH b's tiles: 7 coalesced b128 per thread ----
    const short8* src = (const short8*)(bft + (size_t)(bg * BPB) * BFT_N);
    short8 st[7];
#pragma unroll
    for (int k = 0; k < 7; ++k) st[k] = src[t + k * 256];   // 1792 = 7*256

    // ---- 2. this wave's n-params: 14 b128 gathers (overlap with above) ----
    bf16x8 alA[3][2], whB[4][2];
    {
        const unsigned short* ap = alp + n * ALP_N;
        const unsigned short* wp = whp + n * WHP_N;
#pragma unroll
        for (int m = 0; m < 3; ++m)
#pragma unroll
            for (int s = 0; s < 2; ++s)
                alA[m][s] = ld_frag(&ap[(m * 16 + l15) * 64 + s * 32 + fo]);
#pragma unroll
        for (int tt = 0; tt < 4; ++tt)
#pragma unroll
            for (int s = 0; s < 2; ++s)
                whB[tt][s] = ld_frag(&wp[(tt * 16 + l15) * 64 + s * 32 + fo]);
    }

    // ---- 3. linear conflict-free ds_write_b128, ONE barrier ----
#pragma unroll
    for (int k = 0; k < 7; ++k)
        *(short8*)&sBuf[(size_t)(t + k * 256) * 8] = st[k];
    __syncthreads();

    // ---- 4. two b's, pure MFMA (no further barriers) ----
#pragma unroll
    for (int j = 0; j < BPB; ++j) {
        const unsigned short* sb = &sBuf[j * BFT_N];
        const int b = bg * BPB + j;

        bf16x8 biA[3][2];
#pragma unroll
        for (int m = 0; m < 3; ++m)
#pragma unroll
            for (int s = 0; s < 2; ++s) {
                const int row = m * 16 + l15;
                const int pch = ((s * 4 + quad) ^ (row & 7)) << 3;
                biA[m][s] = ld_frag(&sb[BI_OFF + row * 64 + pch]);
            }

        float p[4];
#pragma unroll
        for (int tt = 0; tt < 4; ++tt) {
            const int row = tt * 16 + l15;
            const int pc0 = ((0 + quad) ^ (row & 7)) << 3;
            const int pc1 = ((4 + quad) ^ (row & 7)) << 3;
            bf16x8 bb0 = ld_frag(&sb[B0T_OFF + row * 64 + pc0]);
            bf16x8 bb1 = ld_frag(&sb[B0T_OFF + row * 64 + pc1]);
            float acc = 0.f;
#pragma unroll
            for (int m = 0; m < 3; ++m) {
                f32x4 z = {0.f, 0.f, 0.f, 0.f};
                f32x4 T = mfma16(biA[m][0], whB[tt][0], z);
                T = mfma16(biA[m][1], whB[tt][1], T);
                f32x4 G = mfma16(alA[m][0], bb0, z);
                G = mfma16(alA[m][1], bb1, G);
                acc += T[0] * G[0] + T[1] * G[1] + T[2] * G[2] + T[3] * G[3];
            }
            p[tt] = acc;
        }
#pragma unroll
        for (int tt = 0; tt < 4; ++tt) {
            p[tt] += __shfl_xor(p[tt], 16, 64);
            p[tt] += __shfl_xor(p[tt], 32, 64);
        }
        float v = (quad == 0) ? p[0] : (quad == 1) ? p[1] : (quad == 2) ? p[2] : p[3];
        out[((size_t)b * NN + n) * ED + lane] = v;
    }
}

// ==========================================================================
// TIER 0 (R2-verified): no-ws fallback.
// ==========================================================================
#define PS 72

__device__ __forceinline__ bf16x8 mk_al_frag(const float* __restrict__ alpha,
        int n, int m, int s, int l15, int quad) {
    bf16x8 r;
    const int row = m * 16 + l15;
    const int f0 = s * 32 + quad * 8;
#pragma unroll
    for (int j = 0; j < 8; ++j) {
        const int f = f0 + j;
        float v = (row < NI && f < NF) ? alpha[(f * NI + row) * NN + n] : 0.f;
        r[j] = (__bf16)v;
    }
    return r;
}
__device__ __forceinline__ bf16x8 mk_wh_frag(const float* __restrict__ W,
        const float* __restrict__ h, int n, int tt, int s, int l15, int quad) {
    bf16x8 r;
    const int row = tt * 16 + l15;
    const int k0 = s * 32 + quad * 8;
#pragma unroll
    for (int j = 0; j < 8; ++j) {
        float v = W[n * ED * ED + row * ED + k0 + j] * h[n * ED + k0 + j];
        r[j] = (__bf16)v;
    }
    return r;
}

__global__ __launch_bounds__(256) void gif_mfma(
        const float* __restrict__ B0, const float* __restrict__ Bi,
        const float* __restrict__ W, const float* __restrict__ alpha,
        const float* __restrict__ h, float* __restrict__ out) {
    const int q = blockIdx.x >> 8;
    const int b = blockIdx.x & 255;

    __shared__ __align__(16) unsigned short sBi[48 * PS];
    __shared__ __align__(16) unsigned short sBT[ED * PS];

    const int t = threadIdx.x;
    for (int idx = t; idx < 48 * PS; idx += 256) {
        int i = idx / PS, c = idx - i * PS;
        sBi[idx] = (i < NI && c < ED) ? f2bf(Bi[b * NI * ED + i * ED + c])
                                      : (unsigned short)0;
    }
    for (int idx = t; idx < ED * PS; idx += 256) {
        int D = idx / PS, c = idx - D * PS;
        sBT[idx] = (c < NF) ? f2bf(B0[b * NF * ED + c * ED + D])
                            : (unsigned short)0;
    }
    __syncthreads();

    const int lane = t & 63, w = t >> 6;
    const int quad = lane >> 4, l15 = lane & 15;
    const int fragoff = quad * 8;

    bf16x8 biA[3][2], b0B[4][2];
#pragma unroll
    for (int m = 0; m < 3; ++m)
#pragma unroll
        for (int s = 0; s < 2; ++s)
            biA[m][s] = ld_frag(&sBi[(m * 16 + l15) * PS + s * 32 + fragoff]);
#pragma unroll
    for (int tt = 0; tt < 4; ++tt)
#pragma unroll
        for (int s = 0; s < 2; ++s)
            b0B[tt][s] = ld_frag(&sBT[(tt * 16 + l15) * PS + s * 32 + fragoff]);

#pragma unroll
    for (int rep = 0; rep < 2; ++rep) {
        const int n = q * 8 + w + rep * 4;

        bf16x8 alA[3][2];
#pragma unroll
        for (int m = 0; m < 3; ++m)
#pragma unroll
            for (int s = 0; s < 2; ++s)
                alA[m][s] = mk_al_frag(alpha, n, m, s, l15, quad);

        float p[4];
#pragma unroll
        for (int tt = 0; tt < 4; ++tt) {
            bf16x8 whB2[2];
            whB2[0] = mk_wh_frag(W, h, n, tt, 0, l15, quad);
            whB2[1] = mk_wh_frag(W, h, n, tt, 1, l15, quad);
            float acc = 0.f;
#pragma unroll
            for (int m = 0; m < 3; ++m) {
                f32x4 z = {0.f, 0.f, 0.f, 0.f};
                f32x4 T = mfma16(biA[m][0], whB2[0], z);
                T = mfma16(biA[m][1], whB2[1], T);
                f32x4 G = mfma16(alA[m][0], b0B[tt][0], z);
                G = mfma16(alA[m][1], b0B[tt][1], G);
                acc += T[0] * G[0] + T[1] * G[1] + T[2] * G[2] + T[3] * G[3];
            }
            p[tt] = acc;
        }
#pragma unroll
        for (int tt = 0; tt < 4; ++tt) {
            p[tt] += __shfl_xor(p[tt], 16, 64);
            p[tt] += __shfl_xor(p[tt], 32, 64);
        }
        float v = (quad == 0) ? p[0] : (quad == 1) ? p[1] : (quad == 2) ? p[2] : p[3];
        out[(b * NN + n) * ED + lane] = v;
    }
}

// ==========================================================================
extern "C" void kernel_launch(void* const* d_in, const int* in_sizes, int n_in,
                              void* d_out, int out_size, void* d_ws, size_t ws_size,
                              hipStream_t stream) {
    const float* B0    = (const float*)d_in[0];  // (256,40,64)
    const float* Bi    = (const float*)d_in[1];  // (256,40,64)
    const float* W     = (const float*)d_in[2];  // (40,64,64)
    const float* alpha = (const float*)d_in[3];  // (40,40,40)
    const float* h     = (const float*)d_in[4];  // (40,64,1)
    float* out = (float*)d_out;                  // (256,40,64)

    const size_t need = (size_t)(NN * WHP_N + NN * ALP_N + NB * BFT_N)
                        * sizeof(unsigned short);
    if (ws_size >= need) {
        unsigned short* whp = (unsigned short*)d_ws;
        unsigned short* alp = whp + (size_t)NN * WHP_N;
        unsigned short* bft = alp + (size_t)NN * ALP_N;
        gif_prep5<<<NN + NF + NB, 256, 0, stream>>>(B0, Bi, W, alpha, h,
                                                    whp, alp, bft);
        gif_main9<<<dim3(NB / BPB, 10), 256, 0, stream>>>(whp, alp, bft, out);
        return;
    }

    gif_mfma<<<5 * NB, 256, 0, stream>>>(B0, Bi, W, alpha, h, out);
}